// Round 5
// baseline (328.898 us; speedup 1.0000x reference)
//
#include <hip/hip_runtime.h>
#include <math.h>

// B=2, L=2048, H=8, E=64. Outputs: V [B,L,H,E] then SA [B,H,L,S], fp32.
#define L_DIM 2048
#define H_DIM 8
#define ROWSTRIDE 512                 // H*E floats between consecutive l
#define NT 512
// 0.125 * log2(e): scores computed in log2 domain -> raw v_exp_f32 for softmax
#define QSCALE 0.18033688011112042f
#define FLT_BIG 3.402823466e+38f

typedef __attribute__((ext_vector_type(8))) short short8;
typedef __attribute__((ext_vector_type(4))) float floatx4;

__device__ __forceinline__ float fexp2(float x) {
#if __has_builtin(__builtin_amdgcn_exp2f)
    return __builtin_amdgcn_exp2f(x);   // raw v_exp_f32
#else
    return exp2f(x);
#endif
}

__device__ __forceinline__ float flog2(float x) {
#if __has_builtin(__builtin_amdgcn_logf)
    return __builtin_amdgcn_logf(x);    // raw v_log_f32 (base-2)
#else
    return log2f(x);
#endif
}

// packed fp32x2 -> bf16x2 (RNE), one VALU op for two elements
__device__ __forceinline__ unsigned int cvtpk(float lo, float hi) {
    unsigned int r;
    asm("v_cvt_pk_bf16_f32 %0, %1, %2" : "=v"(r) : "v"(lo), "v"(hi));
    return r;
}

__device__ __forceinline__ short8 pack8(float4 a, float4 b) {
    union { unsigned int u[4]; short8 v; } pk;
    pk.u[0] = cvtpk(a.x, a.y); pk.u[1] = cvtpk(a.z, a.w);
    pk.u[2] = cvtpk(b.x, b.y); pk.u[3] = cvtpk(b.z, b.w);
    return pk.v;
}

__device__ __forceinline__ short8 pack8q(float4 a, float4 b) {
    union { unsigned int u[4]; short8 v; } pk;
    pk.u[0] = cvtpk(a.x * QSCALE, a.y * QSCALE);
    pk.u[1] = cvtpk(a.z * QSCALE, a.w * QSCALE);
    pk.u[2] = cvtpk(b.x * QSCALE, b.y * QSCALE);
    pk.u[3] = cvtpk(b.z * QSCALE, b.w * QSCALE);
    return pk.v;
}

// Swizzled short-index within a [64][64] bf16 tile. Rows are 128B = 8 x 16B
// blocks; phys block = logical block ^ (row&7). Preserves col&7 (so b32/b128
// alignment holds). Bijective per row.
__device__ __forceinline__ int swz(int row, int col) {
    return (row << 6) + ((((col >> 3) ^ (row & 7)) << 3) | (col & 7));
}

// 512 blocks x 512 threads (8 waves). XCD = bid&7 hosts head h=bid&7 (both
// batches: K+V = 2MB, L2-resident). Within an XCD, m=bid>>3 (0..63) decodes
// b=m&1, k=m>>1; qmap(k) = k<16 ? k : 47-k (bijective, qmap(k)+qmap(k+16)=31);
// qt = b ? 31-qmap : qmap.
// ROUND-5: this mapping pairs COMPLEMENTARY q-tiles (qt sum=31, uniform 33
// tiles/CU) under BOTH plausible block->CU placements:
//   (m, m+1)  [fill-2-sequential]: b flips, same k  -> qt + qt' = 31
//   (m, m+32) [round-robin-1]:     same b, k vs k+16 -> qt + qt' = 31
// Round-4's decode was complementary only under (m, m+32); under (m, m+1) it
// co-scheduled SAME-qt blocks (worst CU 2x the balanced makespan).
// Everything below the decode is identical to round 4.
__global__ __launch_bounds__(NT, 4)
void attn_mfma7(const float* __restrict__ Q, const float* __restrict__ K,
                const float* __restrict__ Vv, float* __restrict__ outV,
                float* __restrict__ outSA)
{
    __shared__ __align__(16) unsigned char smem[74752];
    unsigned short* Ks = (unsigned short*)(smem);           // [4 buf][64][64] swz, row-permuted s
    unsigned short* Vt = (unsigned short*)(smem + 32768);   // [4 buf][64][64] swz, row=e col=s
    unsigned short* Ps = (unsigned short*)(smem + 65536);   // [64][64] swz
    float* Ml = (float*)(smem + 73728);                     // [2][64]
    float* Ll = (float*)(smem + 74240);                     // [2][64]
    float* Ob = (float*)(smem);                             // [64][65] fp32, overlays Ks

    const int t    = threadIdx.x;
    const int lane = t & 63;
    const int w    = t >> 6;           // wave 0..7
    const int g    = w >> 2;           // s-column group: cols [32g, 32g+32)
    const int wg   = w & 3;            // wave-in-group: rows 16wg..16wg+15
    const int l15  = lane & 15;
    const int quad = lane >> 4;
    const int gc   = g << 5;           // group column base within tile

    const int bid = blockIdx.x;
    const int h   = bid & 7;
    const int b   = (bid >> 3) & 1;
    const int k   = bid >> 4;                  // 0..31
    const int qm  = (k < 16) ? k : (47 - k);   // qmap: bijective, qmap(k)+qmap(k+16)=31
    const int qt  = b ? (31 - qm) : qm;
    const int q0  = qt << 6;
    const int ntiles = qt + 1;
    const int nphase = (ntiles + 1) >> 1;

    const float* Qb = Q  + (size_t)b * L_DIM * ROWSTRIDE + h * 64;
    const float* Kb = K  + (size_t)b * L_DIM * ROWSTRIDE + h * 64;
    const float* Vb = Vv + (size_t)b * L_DIM * ROWSTRIDE + h * 64;
    float* saBase = outSA + (size_t)(b * H_DIM + h) * L_DIM * L_DIM;

    // ---- K staging map: thread handles logical s-row sr, 8 e at col sc.
    // Row-permute within each 32-row group: kq=sr&31 -> phys (kq&1)*16+(kq>>1),
    // so frag jj, lane l15 reads s = gc + 2*l15 + jj.
    const int sr = t >> 3, sc = (t & 7) << 3;
    const int kq = sr & 31;
    const int kpr = (sr & 32) | ((kq & 1) << 4) | (kq >> 1);
    const int kswz = swz(kpr, sc);     // 16B-aligned short8 dest

    // ---- V staging map: thread handles s-rows {2rp, 2rp+1}, 4 e at ec.
    const int rp = t >> 4, ec = (t & 15) << 2;
    const int vswz0 = swz(ec + 0, 2 * rp);   // b32-aligned (col even)
    const int vswz1 = swz(ec + 1, 2 * rp);
    const int vswz2 = swz(ec + 2, 2 * rp);
    const int vswz3 = swz(ec + 3, 2 * rp);

    auto stageK = [&](int bufi, float4 f0, float4 f1) {
        *(short8*)&Ks[(bufi << 12) + kswz] = pack8(f0, f1);
    };
    auto stageV = [&](int bufi, float4 a, float4 bb) {
        unsigned short* Vn = Vt + (bufi << 12);
        *(unsigned int*)&Vn[vswz0] = cvtpk(a.x, bb.x);
        *(unsigned int*)&Vn[vswz1] = cvtpk(a.y, bb.y);
        *(unsigned int*)&Vn[vswz2] = cvtpk(a.z, bb.z);
        *(unsigned int*)&Vn[vswz3] = cvtpk(a.w, bb.w);
    };

    // ---- Q fragments straight from global (scale folded), once per block ----
    short8 aQ0, aQ1;
    {
        const float* qsrc = Qb + (size_t)(q0 + 16 * wg + l15) * ROWSTRIDE + quad * 8;
        aQ0 = pack8q(*(const float4*)(qsrc),      *(const float4*)(qsrc + 4));
        aQ1 = pack8q(*(const float4*)(qsrc + 32), *(const float4*)(qsrc + 36));
    }

    // =================== PASS 1: row max & denom (per-lane online) ===================
    float m_r[4], l_r[4];
#pragma unroll
    for (int r = 0; r < 4; ++r) { m_r[r] = -FLT_BIG; l_r[r] = 0.f; }

    auto compute1 = [&](int bufi, int st) {
        const unsigned short* Kc = Ks + (bufi << 12);
        floatx4 d0, d1;
        {
            short8 b0 = *(const short8*)&Kc[swz(gc + l15, quad * 8)];
            short8 b1 = *(const short8*)&Kc[swz(gc + l15, 32 + quad * 8)];
            floatx4 acc = {0.f, 0.f, 0.f, 0.f};
            acc = __builtin_amdgcn_mfma_f32_16x16x32_bf16(aQ0, b0, acc, 0, 0, 0);
            acc = __builtin_amdgcn_mfma_f32_16x16x32_bf16(aQ1, b1, acc, 0, 0, 0);
            d0 = acc;
        }
        {
            short8 b0 = *(const short8*)&Kc[swz(gc + 16 + l15, quad * 8)];
            short8 b1 = *(const short8*)&Kc[swz(gc + 16 + l15, 32 + quad * 8)];
            floatx4 acc = {0.f, 0.f, 0.f, 0.f};
            acc = __builtin_amdgcn_mfma_f32_16x16x32_bf16(aQ0, b0, acc, 0, 0, 0);
            acc = __builtin_amdgcn_mfma_f32_16x16x32_bf16(aQ1, b1, acc, 0, 0, 0);
            d1 = acc;
        }
        if (st == qt) {          // diagonal tile: mask (s = s0+gc+2*l15 {+1})
            const int scol = (st << 6) + gc + 2 * l15;
#pragma unroll
            for (int r = 0; r < 4; ++r) {
                const int lrow = q0 + 16 * wg + quad * 4 + r;
                float v0 = (scol     <= lrow) ? d0[r] : -INFINITY;
                float v1 = (scol + 1 <= lrow) ? d1[r] : -INFINITY;
                const float mnew = fmaxf(m_r[r], fmaxf(v0, v1));  // finite
                float es = fexp2(v0 - mnew) + fexp2(v1 - mnew);   // exp2(-inf)=0
                l_r[r] = l_r[r] * fexp2(m_r[r] - mnew) + es;
                m_r[r] = mnew;
            }
        } else {
#pragma unroll
            for (int r = 0; r < 4; ++r) {
                float v0 = d0[r], v1 = d1[r];
                const float mnew = fmaxf(m_r[r], fmaxf(v0, v1));
                float es = fexp2(v0 - mnew) + fexp2(v1 - mnew);
                l_r[r] = l_r[r] * fexp2(m_r[r] - mnew) + es;
                m_r[r] = mnew;
            }
        }
    };

    {   // prologue: stage tiles 0 and 1 (dup tile 0 if ntiles==1)
        const int t1 = (ntiles > 1) ? 1 : 0;
        const float* k0 = Kb + (size_t)sr * ROWSTRIDE + sc;
        const float* k1 = Kb + (size_t)((t1 << 6) + sr) * ROWSTRIDE + sc;
        stageK(0, *(const float4*)k0, *(const float4*)(k0 + 4));
        stageK(1, *(const float4*)k1, *(const float4*)(k1 + 4));
    }
    __syncthreads();

    for (int ph = 0; ph < nphase; ++ph) {
        const int base = ph << 1;
        const int pb   = (ph & 1) << 1;
        // prefetch next pair into regs (clamped addresses on the tail)
        const int t2 = (base + 2 < ntiles) ? base + 2 : ntiles - 1;
        const int t3 = (base + 3 < ntiles) ? base + 3 : ntiles - 1;
        const float* k2 = Kb + (size_t)((t2 << 6) + sr) * ROWSTRIDE + sc;
        const float* k3 = Kb + (size_t)((t3 << 6) + sr) * ROWSTRIDE + sc;
        float4 a2 = *(const float4*)k2, b2 = *(const float4*)(k2 + 4);
        float4 a3 = *(const float4*)k3, b3 = *(const float4*)(k3 + 4);

        compute1(pb, base);
        if (base + 1 < ntiles) compute1(pb + 1, base + 1);

        if (base + 2 < ntiles) stageK(pb ^ 2, a2, b2);
        if (base + 3 < ntiles) stageK((pb ^ 2) + 1, a3, b3);
        __syncthreads();
    }

    // ---- merge (m,l) across the 16 lanes owning this row's s-columns ----
#pragma unroll
    for (int r = 0; r < 4; ++r) {
#pragma unroll
        for (int mk = 1; mk < 16; mk <<= 1) {
            float mo = __shfl_xor(m_r[r], mk);
            float lo = __shfl_xor(l_r[r], mk);
            float mn = fmaxf(m_r[r], mo);      // finite always
            l_r[r] = l_r[r] * fexp2(m_r[r] - mn) + lo * fexp2(mo - mn);
            m_r[r] = mn;
        }
    }

    // ---- combine across the two s-column groups via LDS ----
    if (l15 == 0) {
#pragma unroll
        for (int r = 0; r < 4; ++r) {
            const int row = 16 * wg + quad * 4 + r;
            Ml[g * 64 + row] = m_r[r];
            Ll[g * 64 + row] = l_r[r];
        }
    }
    {   // pass-2 prologue: stage K and V^T tiles 0,1 (overlaps m/l combine)
        const int t1 = (ntiles > 1) ? 1 : 0;
        const float* k0 = Kb + (size_t)sr * ROWSTRIDE + sc;
        const float* k1 = Kb + (size_t)((t1 << 6) + sr) * ROWSTRIDE + sc;
        stageK(0, *(const float4*)k0, *(const float4*)(k0 + 4));
        stageK(1, *(const float4*)k1, *(const float4*)(k1 + 4));
        const float* v0p = Vb + (size_t)(2 * rp) * ROWSTRIDE + ec;
        const float* v1p = Vb + (size_t)((t1 << 6) + 2 * rp) * ROWSTRIDE + ec;
        stageV(0, *(const float4*)v0p, *(const float4*)(v0p + ROWSTRIDE));
        stageV(1, *(const float4*)v1p, *(const float4*)(v1p + ROWSTRIDE));
    }
    __syncthreads();

    // c_r = m_final + log2(l_final): p = exp2(v - c_r), normalization folded
    float c_r[4];
#pragma unroll
    for (int r = 0; r < 4; ++r) {
        const int row = 16 * wg + quad * 4 + r;
        float m0 = Ml[row], m1 = Ml[64 + row];
        float l0 = Ll[row], l1 = Ll[64 + row];
        float mf = fmaxf(m0, m1);              // finite (never -inf)
        float lf = l0 * fexp2(m0 - mf) + l1 * fexp2(m1 - mf);  // 0 contrib for all-masked group
        c_r[r] = mf + flog2(lf);
    }

    // =================== PASS 2: SA write + PV ===================
    floatx4 oacc[4];
#pragma unroll
    for (int j = 0; j < 4; ++j) oacc[j] = (floatx4){0.f, 0.f, 0.f, 0.f};

    auto compute2 = [&](int bufi, int st) {
        const unsigned short* Kc = Ks + (bufi << 12);
        const unsigned short* Vc = Vt + (bufi << 12);
        floatx4 d0, d1;
        {
            short8 b0 = *(const short8*)&Kc[swz(gc + l15, quad * 8)];
            short8 b1 = *(const short8*)&Kc[swz(gc + l15, 32 + quad * 8)];
            floatx4 acc = {0.f, 0.f, 0.f, 0.f};
            acc = __builtin_amdgcn_mfma_f32_16x16x32_bf16(aQ0, b0, acc, 0, 0, 0);
            acc = __builtin_amdgcn_mfma_f32_16x16x32_bf16(aQ1, b1, acc, 0, 0, 0);
            d0 = acc;
        }
        {
            short8 b0 = *(const short8*)&Kc[swz(gc + 16 + l15, quad * 8)];
            short8 b1 = *(const short8*)&Kc[swz(gc + 16 + l15, 32 + quad * 8)];
            floatx4 acc = {0.f, 0.f, 0.f, 0.f};
            acc = __builtin_amdgcn_mfma_f32_16x16x32_bf16(aQ0, b0, acc, 0, 0, 0);
            acc = __builtin_amdgcn_mfma_f32_16x16x32_bf16(aQ1, b1, acc, 0, 0, 0);
            d1 = acc;
        }
        const int s0 = st << 6;
        const int scol = s0 + gc + 2 * l15;
        if (st == qt) {          // diagonal tile: masked path
#pragma unroll
            for (int r = 0; r < 4; ++r) {
                const int lrow = q0 + 16 * wg + quad * 4 + r;
                const float cr = c_r[r];
                float p0 = (scol     <= lrow) ? fexp2(d0[r] - cr) : 0.0f;
                float p1 = (scol + 1 <= lrow) ? fexp2(d1[r] - cr) : 0.0f;
                float2 pr; pr.x = p0; pr.y = p1;
                *(float2*)(saBase + (size_t)lrow * L_DIM + scol) = pr;
                *(unsigned int*)&Ps[swz(16 * wg + quad * 4 + r, gc + 2 * l15)] = cvtpk(p0, p1);
            }
        } else {                 // interior tile: no masking
#pragma unroll
            for (int r = 0; r < 4; ++r) {
                const int lrow = q0 + 16 * wg + quad * 4 + r;
                const float cr = c_r[r];
                float p0 = fexp2(d0[r] - cr);
                float p1 = fexp2(d1[r] - cr);
                float2 pr; pr.x = p0; pr.y = p1;
                *(float2*)(saBase + (size_t)lrow * L_DIM + scol) = pr;
                *(unsigned int*)&Ps[swz(16 * wg + quad * 4 + r, gc + 2 * l15)] = cvtpk(p0, p1);
            }
        }
        // PV over this group's 32 s-cols: Ps rows/col-halves are wave-private;
        // compiler's in-order lgkmcnt covers the RAW.
        short8 aP = *(const short8*)&Ps[swz(16 * wg + l15, gc + quad * 8)];
#pragma unroll
        for (int j = 0; j < 4; ++j) {
            short8 bv = *(const short8*)&Vc[swz(16 * j + l15, gc + quad * 8)];
            oacc[j] = __builtin_amdgcn_mfma_f32_16x16x32_bf16(aP, bv, oacc[j], 0, 0, 0);
        }
    };

    for (int ph = 0; ph < nphase; ++ph) {
        const int base = ph << 1;
        const int pb   = (ph & 1) << 1;
        const int t2 = (base + 2 < ntiles) ? base + 2 : ntiles - 1;
        const int t3 = (base + 3 < ntiles) ? base + 3 : ntiles - 1;
        const float* k2 = Kb + (size_t)((t2 << 6) + sr) * ROWSTRIDE + sc;
        const float* k3 = Kb + (size_t)((t3 << 6) + sr) * ROWSTRIDE + sc;
        const float* v2 = Vb + (size_t)((t2 << 6) + 2 * rp) * ROWSTRIDE + ec;
        const float* v3 = Vb + (size_t)((t3 << 6) + 2 * rp) * ROWSTRIDE + ec;
        float4 ka2 = *(const float4*)k2, kb2 = *(const float4*)(k2 + 4);
        float4 ka3 = *(const float4*)k3, kb3 = *(const float4*)(k3 + 4);
        float4 va2 = *(const float4*)v2, vb2 = *(const float4*)(v2 + ROWSTRIDE);
        float4 va3 = *(const float4*)v3, vb3 = *(const float4*)(v3 + ROWSTRIDE);

        compute2(pb, base);
        if (base + 1 < ntiles) compute2(pb + 1, base + 1);

        if (base + 2 < ntiles) { stageK(pb ^ 2, ka2, kb2); stageV(pb ^ 2, va2, vb2); }
        if (base + 3 < ntiles) { stageK((pb ^ 2) + 1, ka3, kb3); stageV((pb ^ 2) + 1, va3, vb3); }
        __syncthreads();
    }

    // ---- combine partial O across groups (Ob overlays Ks; safe after barrier) ----
    if (g == 1) {
#pragma unroll
        for (int r = 0; r < 4; ++r) {
            const int row = 16 * wg + quad * 4 + r;
#pragma unroll
            for (int j = 0; j < 4; ++j)
                Ob[row * 65 + 16 * j + l15] = oacc[j][r];
        }
    }
    __syncthreads();
    if (g == 0) {
#pragma unroll
        for (int r = 0; r < 4; ++r) {
            const int row = 16 * wg + quad * 4 + r;
            float* op = outV + ((size_t)b * L_DIM + q0 + row) * ROWSTRIDE + h * 64 + l15;
#pragma unroll
            for (int j = 0; j < 4; ++j)
                op[16 * j] = oacc[j][r] + Ob[row * 65 + 16 * j + l15];
        }
    }

    // ---- zero-fill SA above the diagonal tile (d_out is poisoned) ----
    {
        const int z0 = ntiles << 6;
        const int zr = t >> 3;               // 64 rows, 8 threads/row
        float* rowp = saBase + (size_t)(q0 + zr) * L_DIM;
        const float4 zf = {0.f, 0.f, 0.f, 0.f};
        for (int s = z0 + (t & 7) * 4; s < L_DIM; s += 32)
            *(float4*)(rowp + s) = zf;
    }
}

extern "C" void kernel_launch(void* const* d_in, const int* in_sizes, int n_in,
                              void* d_out, int out_size, void* d_ws, size_t ws_size,
                              hipStream_t stream) {
    const float* Q  = (const float*)d_in[0];
    const float* K  = (const float*)d_in[1];
    const float* Vv = (const float*)d_in[2];
    float* out   = (float*)d_out;
    float* outV  = out;                                       // [B,L,H,E]
    float* outSA = out + (size_t)2 * L_DIM * H_DIM * 64;      // [B,H,L,S]

    dim3 grid(512);   // complementary q-tile pairs under BOTH (m,m+1) and (m,m+32) co-residency
    dim3 block(NT);
    attn_mfma7<<<grid, block, 0, stream>>>(Q, K, Vv, outV, outSA);
}